// Round 1
// baseline (905.246 us; speedup 1.0000x reference)
//
#include <hip/hip_runtime.h>
#include <cstddef>

#define CH 512
#define SEQ 1024
#define NHEADS 8
#define HDIM 64

union F4 { float4 v; float f[4]; };

// Out[bb][m][n] = sum_k A[m][k] * B[bb][k][n] + bias[m]
// A: (M x K) row-major shared across batch; B: (batch, K, N); Out: (batch, M, N)
// N = SEQ = 1024. Tile 64x64, BK=32, 256 threads, 4x4 micro-tile per thread.
__global__ __launch_bounds__(256) void gemm_bias(
    const float* __restrict__ A, const float* __restrict__ Bmat,
    const float* __restrict__ bias, float* __restrict__ Out,
    int M, int K)
{
  const int N = SEQ;
  const int n0 = blockIdx.x * 64;
  const int m0 = blockIdx.y * 64;
  const int bb = blockIdx.z;
  const float* __restrict__ Bb = Bmat + (size_t)bb * K * N;
  float* __restrict__ Ob = Out + (size_t)bb * M * N;

  __shared__ __align__(16) float As[32][68];  // [k][m]
  __shared__ __align__(16) float Bs[32][68];  // [k][n]

  const int t = threadIdx.x;
  const int tr = t >> 4;       // 0..15 -> rows m0 + tr*4 ..
  const int tc = t & 15;       // 0..15 -> cols n0 + tc*4 ..

  float acc[4][4];
  #pragma unroll
  for (int i = 0; i < 4; ++i)
    #pragma unroll
    for (int j = 0; j < 4; ++j) acc[i][j] = 0.f;

  for (int k0 = 0; k0 < K; k0 += 32) {
    // A tile 64x32 -> As[k][m]
    #pragma unroll
    for (int i = t; i < 64 * 32; i += 256) {
      int m = i >> 5, kk = i & 31;
      As[kk][m] = A[(size_t)(m0 + m) * K + (k0 + kk)];
    }
    // B tile 32x64 -> Bs[k][n]
    #pragma unroll
    for (int i = t; i < 32 * 64; i += 256) {
      int kk = i >> 6, n = i & 63;
      Bs[kk][n] = Bb[(size_t)(k0 + kk) * N + (n0 + n)];
    }
    __syncthreads();
    #pragma unroll
    for (int kk = 0; kk < 32; ++kk) {
      F4 a4, b4;
      a4.v = *(const float4*)&As[kk][tr * 4];
      b4.v = *(const float4*)&Bs[kk][tc * 4];
      #pragma unroll
      for (int i = 0; i < 4; ++i)
        #pragma unroll
        for (int j = 0; j < 4; ++j)
          acc[i][j] = fmaf(a4.f[i], b4.f[j], acc[i][j]);
    }
    __syncthreads();
  }

  #pragma unroll
  for (int i = 0; i < 4; ++i) {
    float bv = bias[m0 + tr * 4 + i];
    F4 o;
    #pragma unroll
    for (int j = 0; j < 4; ++j) o.f[j] = acc[i][j] + bv;
    *(float4*)&Ob[(size_t)(m0 + tr * 4 + i) * N + n0 + tc * 4] = o.v;
  }
}

// Flash-style attention. qkv: (b, 3*CH, SEQ) with rows [Q(512) | K(512) | V(512)],
// row j = n*HDIM + d. av out: (b, CH, SEQ).
// One block per (q-tile of 64, head, batch). 256 threads, 4x4 micro-tiles.
__global__ __launch_bounds__(256) void attn(
    const float* __restrict__ qkv, float* __restrict__ av)
{
  const int qt = blockIdx.x;   // 0..15
  const int n  = blockIdx.y;   // head 0..7
  const int bb = blockIdx.z;   // batch 0..7
  const int si0 = qt * 64;

  const float* __restrict__ Qg = qkv + ((size_t)bb * 3 * CH + 0 * CH + n * HDIM) * SEQ;
  const float* __restrict__ Kg = qkv + ((size_t)bb * 3 * CH + 1 * CH + n * HDIM) * SEQ;
  const float* __restrict__ Vg = qkv + ((size_t)bb * 3 * CH + 2 * CH + n * HDIM) * SEQ;
  float* __restrict__ avb = av + ((size_t)bb * CH + n * HDIM) * SEQ;

  __shared__ __align__(16) float Qs[64][68];  // [d][qi]
  __shared__ __align__(16) float Ks[64][68];  // [d][kj]
  __shared__ __align__(16) float Vs[64][68];  // [kj][d]
  __shared__ __align__(16) float Ps[64][68];  // [qi][kj]

  const int t = threadIdx.x;
  const int tr = t >> 4;   // qi rows tr*4..+4
  const int tc = t & 15;   // kj cols (scores) / d cols (AV) tc*4..+4

  // load Q tile (64 d x 64 qi), rows contiguous in global
  #pragma unroll
  for (int i = t; i < 64 * 64; i += 256) {
    int d = i >> 6, qi = i & 63;
    Qs[d][qi] = Qg[(size_t)d * SEQ + si0 + qi];
  }

  float mrow[4], lrow[4], O[4][4];
  #pragma unroll
  for (int i = 0; i < 4; ++i) {
    mrow[i] = -1e30f;
    lrow[i] = 0.f;
    #pragma unroll
    for (int j = 0; j < 4; ++j) O[i][j] = 0.f;
  }

  for (int kt = 0; kt < 16; ++kt) {
    __syncthreads();  // previous AV done with Vs/Ps
    #pragma unroll
    for (int i = t; i < 64 * 64; i += 256) {
      int d = i >> 6, kj = i & 63;
      Ks[d][kj] = Kg[(size_t)d * SEQ + kt * 64 + kj];
      Vs[kj][d] = Vg[(size_t)d * SEQ + kt * 64 + kj];
    }
    __syncthreads();

    // scores S[qi][kj] = 0.125 * sum_d Q[d][qi] * K[d][kj]
    float s[4][4];
    #pragma unroll
    for (int i = 0; i < 4; ++i)
      #pragma unroll
      for (int j = 0; j < 4; ++j) s[i][j] = 0.f;
    #pragma unroll
    for (int d = 0; d < 64; ++d) {
      F4 q4, k4;
      q4.v = *(const float4*)&Qs[d][tr * 4];
      k4.v = *(const float4*)&Ks[d][tc * 4];
      #pragma unroll
      for (int i = 0; i < 4; ++i)
        #pragma unroll
        for (int j = 0; j < 4; ++j)
          s[i][j] = fmaf(q4.f[i], k4.f[j], s[i][j]);
    }

    // scale + tile row max (reduce over 16 lanes sharing tr)
    float tm[4];
    #pragma unroll
    for (int i = 0; i < 4; ++i) {
      s[i][0] *= 0.125f; s[i][1] *= 0.125f; s[i][2] *= 0.125f; s[i][3] *= 0.125f;
      tm[i] = fmaxf(fmaxf(s[i][0], s[i][1]), fmaxf(s[i][2], s[i][3]));
    }
    #pragma unroll
    for (int off = 1; off < 16; off <<= 1)
      #pragma unroll
      for (int i = 0; i < 4; ++i)
        tm[i] = fmaxf(tm[i], __shfl_xor(tm[i], off));

    // online softmax update
    float mn[4], al[4], rs[4];
    float p[4][4];
    #pragma unroll
    for (int i = 0; i < 4; ++i) {
      mn[i] = fmaxf(mrow[i], tm[i]);
      al[i] = __expf(mrow[i] - mn[i]);   // first tile: exp(-inf)=0
      rs[i] = 0.f;
      #pragma unroll
      for (int j = 0; j < 4; ++j) {
        p[i][j] = __expf(s[i][j] - mn[i]);
        rs[i] += p[i][j];
      }
    }
    #pragma unroll
    for (int off = 1; off < 16; off <<= 1)
      #pragma unroll
      for (int i = 0; i < 4; ++i)
        rs[i] += __shfl_xor(rs[i], off);
    #pragma unroll
    for (int i = 0; i < 4; ++i) {
      lrow[i] = lrow[i] * al[i] + rs[i];
      mrow[i] = mn[i];
      #pragma unroll
      for (int j = 0; j < 4; ++j) O[i][j] *= al[i];
      #pragma unroll
      for (int j = 0; j < 4; ++j) Ps[tr * 4 + i][tc * 4 + j] = p[i][j];
    }
    __syncthreads();

    // AV: O[qi][d] += sum_kj P[qi][kj] * V[kj][d]
    #pragma unroll
    for (int kb = 0; kb < 16; ++kb) {
      F4 p4[4];
      #pragma unroll
      for (int i = 0; i < 4; ++i) p4[i].v = *(const float4*)&Ps[tr * 4 + i][kb * 4];
      #pragma unroll
      for (int u = 0; u < 4; ++u) {
        F4 v4;
        v4.v = *(const float4*)&Vs[kb * 4 + u][tc * 4];
        #pragma unroll
        for (int i = 0; i < 4; ++i) {
          float pp = p4[i].f[u];
          #pragma unroll
          for (int j = 0; j < 4; ++j)
            O[i][j] = fmaf(pp, v4.f[j], O[i][j]);
        }
      }
    }
  }

  // finalize: av[(n*HDIM + d)][si] = O / l
  #pragma unroll
  for (int i = 0; i < 4; ++i) {
    float inv = 1.f / lrow[i];
    #pragma unroll
    for (int j = 0; j < 4; ++j)
      avb[(size_t)(tc * 4 + j) * SEQ + si0 + tr * 4 + i] = O[i][j] * inv;
  }
}

extern "C" void kernel_launch(void* const* d_in, const int* in_sizes, int n_in,
                              void* d_out, int out_size, void* d_ws, size_t ws_size,
                              hipStream_t stream) {
  const float* x     = (const float*)d_in[0];  // (8, 512, 32, 32) = (b, c, s)
  const float* w_qkv = (const float*)d_in[1];  // (1536, 512)
  const float* b_qkv = (const float*)d_in[2];  // (1536,)
  const float* w_o   = (const float*)d_in[3];  // (512, 512)
  const float* b_o   = (const float*)d_in[4];  // (512,)
  float* out = (float*)d_out;                  // (8, 512, 1024)

  float* qkv_ws = (float*)d_ws;                          // 8*1536*1024 floats
  float* av_ws  = qkv_ws + (size_t)8 * 3 * CH * SEQ;     // 8*512*1024 floats

  dim3 blk(256);
  // Phase 1: qkv (b, 1536, s) = w_qkv @ x[b] + b_qkv
  gemm_bias<<<dim3(SEQ / 64, (3 * CH) / 64, 8), blk, 0, stream>>>(
      w_qkv, x, b_qkv, qkv_ws, 3 * CH, CH);
  // Phase 2: attention -> av (b, c, s)
  attn<<<dim3(SEQ / 64, NHEADS, 8), blk, 0, stream>>>(qkv_ws, av_ws);
  // Phase 3: out (b, c, s) = w_o @ av[b] + b_o
  gemm_bias<<<dim3(SEQ / 64, CH / 64, 8), blk, 0, stream>>>(
      w_o, av_ws, b_o, out, CH, CH);
}

// Round 3
// 215.088 us; speedup vs baseline: 4.2087x; 4.2087x over previous
//
#include <hip/hip_runtime.h>
#include <cstddef>
#include <cstdint>

#define CH 512
#define SEQ 1024
#define NH 8
#define HD 64

typedef unsigned short u16;
typedef __attribute__((ext_vector_type(8))) short bf16x8;   // 8 bf16 (4 VGPRs), guide §3 form
typedef __attribute__((ext_vector_type(4))) float f32x4;
typedef __attribute__((ext_vector_type(4))) unsigned short u16x4;

__device__ __forceinline__ u16 f2bf(float f) {
  unsigned u = __float_as_uint(f);
  u += 0x7fffu + ((u >> 16) & 1u);
  return (u16)(u >> 16);
}
__device__ __forceinline__ float bf2f(u16 h) {
  return __uint_as_float(((unsigned)h) << 16);
}

__device__ __forceinline__ void gld16(void* lds, const void* g) {
  __builtin_amdgcn_global_load_lds(
      (const __attribute__((address_space(1))) unsigned int*)g,
      (__attribute__((address_space(3))) unsigned int*)lds, 16, 0, 0);
}

__device__ __forceinline__ f32x4 mfma16(bf16x8 a, bf16x8 b, f32x4 c) {
  return __builtin_amdgcn_mfma_f32_16x16x32_bf16(a, b, c, 0, 0, 0);
}

// ---------------- split: fp32 -> bf16 hi + lo ----------------
__global__ __launch_bounds__(256) void split_plain(
    const float* __restrict__ in, u16* __restrict__ hi, u16* __restrict__ lo, int n4)
{
  int i = blockIdx.x * 256 + threadIdx.x;
  if (i < n4) {
    float4 v = ((const float4*)in)[i];
    float vv0 = v.x, vv1 = v.y, vv2 = v.z, vv3 = v.w;
    u16x4 h, l;
    h[0] = f2bf(vv0); l[0] = f2bf(vv0 - bf2f(h[0]));
    h[1] = f2bf(vv1); l[1] = f2bf(vv1 - bf2f(h[1]));
    h[2] = f2bf(vv2); l[2] = f2bf(vv2 - bf2f(h[2]));
    h[3] = f2bf(vv3); l[3] = f2bf(vv3 - bf2f(h[3]));
    ((u16x4*)hi)[i] = h;
    ((u16x4*)lo)[i] = l;
  }
}

// x (b, 512 c, 1024 s) fp32 -> xt_hi/lo (b, 1024 s, 512 c) bf16
__global__ __launch_bounds__(256) void transpose_split(
    const float* __restrict__ x, u16* __restrict__ xh, u16* __restrict__ xl)
{
  __shared__ float tile[64][65];
  const int s0 = blockIdx.x * 64, c0 = blockIdx.y * 64, bz = blockIdx.z;
  const int t = threadIdx.x;
  #pragma unroll
  for (int p = 0; p < 16; ++p) {
    int i = p * 256 + t;
    int cl = i >> 6, sl = i & 63;
    tile[cl][sl] = x[((size_t)bz * CH + c0 + cl) * SEQ + s0 + sl];
  }
  __syncthreads();
  #pragma unroll
  for (int p = 0; p < 16; ++p) {
    int i = p * 256 + t;
    int sl = i >> 6, cl = i & 63;
    float v = tile[cl][sl];
    u16 h = f2bf(v);
    size_t idx = ((size_t)bz * SEQ + s0 + sl) * CH + c0 + cl;
    xh[idx] = h;
    xl[idx] = f2bf(v - bf2f(h));
  }
}

// ---------------- hi/lo split-bf16 GEMM ----------------
// C(bz) = A(MxK=512) * BT(bz, N=1024, K=512)^T + bias
// MODE 0: o0 = fp32 out (b, 512, 1024)
// MODE 1: qkv epilogue -> o0..o4 = q_hi,q_lo,k_hi,k_lo,v_hi
template<int MODE>
__global__ __launch_bounds__(256, 2) void gemm_hilo(
    const u16* __restrict__ Ah, const u16* __restrict__ Al,
    const u16* __restrict__ BTh, const u16* __restrict__ BTl,
    const float* __restrict__ bias,
    void* __restrict__ o0, void* __restrict__ o1, void* __restrict__ o2,
    void* __restrict__ o3, void* __restrict__ o4)
{
  const int bx = blockIdx.x, by = blockIdx.y, bz = blockIdx.z;
  const int m0 = by * 128, n0 = bx * 128;
  const char* Ahc = (const char*)Ah;
  const char* Alc = (const char*)Al;
  const char* Bhc = (const char*)BTh + (size_t)bz * SEQ * CH * 2;
  const char* Blc = (const char*)BTl + (size_t)bz * SEQ * CH * 2;

  // rows of 128B: [32 bf16 hi | 32 bf16 lo], XOR-swizzled by (row&7)<<4
  __shared__ __align__(16) u16 As[128 * 64];
  __shared__ __align__(16) u16 Bs[128 * 64];

  const int t = threadIdx.x, w = t >> 6, lane = t & 63;
  const int lr = lane & 15, lg = lane >> 4;
  const int wr = w >> 1, wc = w & 1;

  f32x4 acc[4][4];
  #pragma unroll
  for (int i = 0; i < 4; ++i)
    #pragma unroll
    for (int j = 0; j < 4; ++j) acc[i][j] = (f32x4){0.f, 0.f, 0.f, 0.f};

  for (int k0 = 0; k0 < CH; k0 += 32) {
    __syncthreads();
    #pragma unroll
    for (int p = 0; p < 4; ++p) {
      const int ldsoff = p * 4096 + w * 1024 + lane * 16;
      const int m = ldsoff >> 7;
      const int W = ldsoff & 127;
      const int Wp = W ^ ((m & 7) << 4);
      const char* src = (Wp < 64 ? Ahc : Alc) + ((size_t)(m0 + m) * CH + k0) * 2 + (Wp & 63);
      gld16((char*)As + p * 4096 + w * 1024, src);
    }
    #pragma unroll
    for (int p = 0; p < 4; ++p) {
      const int ldsoff = p * 4096 + w * 1024 + lane * 16;
      const int n = ldsoff >> 7;
      const int W = ldsoff & 127;
      const int Wp = W ^ ((n & 7) << 4);
      const char* src = (Wp < 64 ? Bhc : Blc) + ((size_t)(n0 + n) * CH + k0) * 2 + (Wp & 63);
      gld16((char*)Bs + p * 4096 + w * 1024, src);
    }
    __syncthreads();

    bf16x8 Afh[4], Afl[4], Bfh[4], Bfl[4];
    #pragma unroll
    for (int mi = 0; mi < 4; ++mi) {
      const int m = wr * 64 + mi * 16 + lr;
      const int swz = (m & 7) << 4;
      Afh[mi] = *(const bf16x8*)((const char*)As + m * 128 + ((lg * 16) ^ swz));
      Afl[mi] = *(const bf16x8*)((const char*)As + m * 128 + ((64 + lg * 16) ^ swz));
    }
    #pragma unroll
    for (int ni = 0; ni < 4; ++ni) {
      const int n = wc * 64 + ni * 16 + lr;
      const int swz = (n & 7) << 4;
      Bfh[ni] = *(const bf16x8*)((const char*)Bs + n * 128 + ((lg * 16) ^ swz));
      Bfl[ni] = *(const bf16x8*)((const char*)Bs + n * 128 + ((64 + lg * 16) ^ swz));
    }
    #pragma unroll
    for (int mi = 0; mi < 4; ++mi) {
      #pragma unroll
      for (int ni = 0; ni < 4; ++ni) {
        acc[mi][ni] = mfma16(Afh[mi], Bfh[ni], acc[mi][ni]);
        acc[mi][ni] = mfma16(Afh[mi], Bfl[ni], acc[mi][ni]);
        acc[mi][ni] = mfma16(Afl[mi], Bfh[ni], acc[mi][ni]);
      }
    }
  }

  if constexpr (MODE == 0) {
    float* Out = (float*)o0 + (size_t)bz * CH * SEQ;
    #pragma unroll
    for (int mi = 0; mi < 4; ++mi) {
      const int mb = m0 + wr * 64 + mi * 16 + lg * 4;
      #pragma unroll
      for (int r = 0; r < 4; ++r) {
        const float bv = bias[mb + r];
        #pragma unroll
        for (int ni = 0; ni < 4; ++ni) {
          const int n = n0 + wc * 64 + ni * 16 + lr;
          Out[(size_t)(mb + r) * SEQ + n] = acc[mi][ni][r] + bv;
        }
      }
    }
  } else {
    u16* qh = (u16*)o0; u16* ql = (u16*)o1;
    u16* kh = (u16*)o2; u16* kl = (u16*)o3;
    u16* vh = (u16*)o4;
    #pragma unroll
    for (int mi = 0; mi < 4; ++mi) {
      const int mb = m0 + wr * 64 + mi * 16 + lg * 4;   // 4 consecutive m rows
      const int sec = mb >> 9;                          // 0=q 1=k 2=v
      const int h = (mb >> 6) & 7;
      const int d = mb & 63;
      const size_t bh = (size_t)bz * NH + h;
      const float b0 = bias[mb + 0], b1 = bias[mb + 1], b2 = bias[mb + 2], b3 = bias[mb + 3];
      #pragma unroll
      for (int ni = 0; ni < 4; ++ni) {
        const int n = n0 + wc * 64 + ni * 16 + lr;      // s
        const float c0 = acc[mi][ni][0] + b0;
        const float c1 = acc[mi][ni][1] + b1;
        const float c2 = acc[mi][ni][2] + b2;
        const float c3 = acc[mi][ni][3] + b3;
        if (sec == 2) {
          u16* dst = vh + (bh * HD + d) * SEQ + n;      // v transposed (b,h,d,s)
          dst[0 * SEQ] = f2bf(c0);
          dst[1 * SEQ] = f2bf(c1);
          dst[2 * SEQ] = f2bf(c2);
          dst[3 * SEQ] = f2bf(c3);
        } else {
          u16* dsth = (sec == 0 ? qh : kh) + (bh * SEQ + n) * HD + d;
          u16* dstl = (sec == 0 ? ql : kl) + (bh * SEQ + n) * HD + d;
          u16x4 hv, lv;
          hv[0] = f2bf(c0); lv[0] = f2bf(c0 - bf2f(hv[0]));
          hv[1] = f2bf(c1); lv[1] = f2bf(c1 - bf2f(hv[1]));
          hv[2] = f2bf(c2); lv[2] = f2bf(c2 - bf2f(hv[2]));
          hv[3] = f2bf(c3); lv[3] = f2bf(c3 - bf2f(hv[3]));
          *(u16x4*)dsth = hv;
          *(u16x4*)dstl = lv;
        }
      }
    }
  }
}

// ---------------- flash attention, MFMA ----------------
// q,k: (b,h,1024,64) hi/lo bf16; v: (b,h,64,1024) bf16; out avt: (b,1024,512) hi/lo
__global__ __launch_bounds__(256, 2) void attn_mfma(
    const u16* __restrict__ q_h, const u16* __restrict__ q_l,
    const u16* __restrict__ k_h, const u16* __restrict__ k_l,
    const u16* __restrict__ v_h,
    u16* __restrict__ av_h, u16* __restrict__ av_l)
{
  const int qt = blockIdx.x, hh = blockIdx.y, bz = blockIdx.z;
  const int bhead = bz * NH + hh;
  const int s0 = qt * 64;
  const int t = threadIdx.x, w = t >> 6, lane = t & 63;
  const int lr = lane & 15, lg = lane >> 4;

  __shared__ __align__(16) u16 Kh_s[64 * 64];   // [kj][d], swizzled
  __shared__ __align__(16) u16 Kl_s[64 * 64];
  __shared__ __align__(16) u16 Vs_s[64 * 64];   // [d][kj], swizzled
  __shared__ __align__(16) u16 Ps_s[4 * 16 * 64]; // per-wave [qi][kj], swizzled

  // Q fragments in registers (wave w owns q-rows s0 + w*16 .. +16)
  bf16x8 QAh[2], QAl[2];
  {
    const size_t qrow = (size_t)bhead * SEQ + s0 + w * 16 + lr;
    #pragma unroll
    for (int ks = 0; ks < 2; ++ks) {
      QAh[ks] = *(const bf16x8*)((const char*)q_h + qrow * 128 + ks * 64 + lg * 16);
      QAl[ks] = *(const bf16x8*)((const char*)q_l + qrow * 128 + ks * 64 + lg * 16);
    }
  }

  float mrow[4], lsum[4];
  f32x4 oacc[4];
  #pragma unroll
  for (int r = 0; r < 4; ++r) { mrow[r] = -1e30f; lsum[r] = 0.f; }
  #pragma unroll
  for (int ni = 0; ni < 4; ++ni) oacc[ni] = (f32x4){0.f, 0.f, 0.f, 0.f};

  for (int kt = 0; kt < 16; ++kt) {
    __syncthreads();   // previous tile fully consumed
    {
      const size_t kbase = (size_t)bhead * SEQ + kt * 64;
      #pragma unroll
      for (int p = 0; p < 2; ++p) {
        const int ldsoff = p * 4096 + w * 1024 + lane * 16;
        const int r = ldsoff >> 7;
        const int W = ldsoff & 127;
        const int Wp = W ^ ((r & 7) << 4);
        gld16((char*)Kh_s + p * 4096 + w * 1024, (const char*)k_h + (kbase + r) * 128 + Wp);
        gld16((char*)Kl_s + p * 4096 + w * 1024, (const char*)k_l + (kbase + r) * 128 + Wp);
        gld16((char*)Vs_s + p * 4096 + w * 1024,
              (const char*)v_h + ((size_t)bhead * HD + r) * 2048 + kt * 128 + Wp);
      }
    }
    __syncthreads();   // staging complete (barrier drains vmcnt)

    // S = Q K^T / 8  (rows qi, cols kj)
    f32x4 sc[4];
    #pragma unroll
    for (int ni = 0; ni < 4; ++ni) sc[ni] = (f32x4){0.f, 0.f, 0.f, 0.f};
    #pragma unroll
    for (int ks = 0; ks < 2; ++ks) {
      #pragma unroll
      for (int ni = 0; ni < 4; ++ni) {
        const int kj = ni * 16 + lr;
        const int off = (ks * 64 + lg * 16) ^ ((kj & 7) << 4);
        bf16x8 kbh = *(const bf16x8*)((const char*)Kh_s + kj * 128 + off);
        bf16x8 kbl = *(const bf16x8*)((const char*)Kl_s + kj * 128 + off);
        sc[ni] = mfma16(QAh[ks], kbh, sc[ni]);
        sc[ni] = mfma16(QAh[ks], kbl, sc[ni]);
        sc[ni] = mfma16(QAl[ks], kbh, sc[ni]);
      }
    }
    #pragma unroll
    for (int ni = 0; ni < 4; ++ni)
      #pragma unroll
      for (int r = 0; r < 4; ++r) sc[ni][r] *= 0.125f;

    // online softmax (row = lg*4+r; its 64 cols live on 16 lr-lanes x 4 frags)
    float tm[4], rs[4], al[4];
    #pragma unroll
    for (int r = 0; r < 4; ++r)
      tm[r] = fmaxf(fmaxf(sc[0][r], sc[1][r]), fmaxf(sc[2][r], sc[3][r]));
    #pragma unroll
    for (int off = 1; off < 16; off <<= 1) {
      #pragma unroll
      for (int r = 0; r < 4; ++r) tm[r] = fmaxf(tm[r], __shfl_xor(tm[r], off));
    }
    #pragma unroll
    for (int r = 0; r < 4; ++r) {
      const float mn = fmaxf(mrow[r], tm[r]);
      al[r] = __expf(mrow[r] - mn);
      mrow[r] = mn;
      rs[r] = 0.f;
    }
    #pragma unroll
    for (int ni = 0; ni < 4; ++ni) {
      #pragma unroll
      for (int r = 0; r < 4; ++r) {
        const float pf = __expf(sc[ni][r] - mrow[r]);
        rs[r] += pf;
        const int qi = lg * 4 + r;
        const int col = ni * 16 + lr;
        *(u16*)((char*)Ps_s + w * 2048 + qi * 128 + ((col * 2) ^ ((qi & 7) << 4))) = f2bf(pf);
      }
    }
    #pragma unroll
    for (int off = 1; off < 16; off <<= 1) {
      #pragma unroll
      for (int r = 0; r < 4; ++r) rs[r] += __shfl_xor(rs[r], off);
    }
    #pragma unroll
    for (int r = 0; r < 4; ++r) lsum[r] = lsum[r] * al[r] + rs[r];
    #pragma unroll
    for (int ni = 0; ni < 4; ++ni)
      #pragma unroll
      for (int r = 0; r < 4; ++r) oacc[ni][r] *= al[r];

    // O += P V   (P is wave-local; same-wave DS ops are ordered)
    #pragma unroll
    for (int ks = 0; ks < 2; ++ks) {
      const int off0 = ks * 64 + lg * 16;
      bf16x8 pa = *(const bf16x8*)((const char*)Ps_s + w * 2048 + lr * 128 + (off0 ^ ((lr & 7) << 4)));
      #pragma unroll
      for (int ni = 0; ni < 4; ++ni) {
        const int d = ni * 16 + lr;
        bf16x8 vb = *(const bf16x8*)((const char*)Vs_s + d * 128 + (off0 ^ ((d & 7) << 4)));
        oacc[ni] = mfma16(pa, vb, oacc[ni]);
      }
    }
  }

  // write avt (b, s, c) hi/lo
  #pragma unroll
  for (int r = 0; r < 4; ++r) {
    const float inv = 1.f / lsum[r];
    const int s = s0 + w * 16 + lg * 4 + r;
    #pragma unroll
    for (int ni = 0; ni < 4; ++ni) {
      const int c = hh * HD + ni * 16 + lr;
      const size_t idx = ((size_t)bz * SEQ + s) * CH + c;
      const float v = oacc[ni][r] * inv;
      const u16 hb = f2bf(v);
      av_h[idx] = hb;
      av_l[idx] = f2bf(v - bf2f(hb));
    }
  }
}

extern "C" void kernel_launch(void* const* d_in, const int* in_sizes, int n_in,
                              void* d_out, int out_size, void* d_ws, size_t ws_size,
                              hipStream_t stream) {
  const float* x     = (const float*)d_in[0];  // (8, 512, 32, 32)
  const float* w_qkv = (const float*)d_in[1];  // (1536, 512)
  const float* b_qkv = (const float*)d_in[2];  // (1536,)
  const float* w_o   = (const float*)d_in[3];  // (512, 512)
  const float* b_o   = (const float*)d_in[4];  // (512,)
  float* out = (float*)d_out;                  // (8, 512, 1024) fp32

  char* ws = (char*)d_ws;
  const size_t SZ = (size_t)8 * SEQ * CH * 2;  // one bf16 plane: 8.39 MB
  u16* xt_h = (u16*)(ws + 0 * SZ);             // also avt_h (aliased; xt dead after gemm1)
  u16* xt_l = (u16*)(ws + 1 * SZ);             // also avt_l
  u16* q_h  = (u16*)(ws + 2 * SZ);
  u16* q_l  = (u16*)(ws + 3 * SZ);
  u16* k_h  = (u16*)(ws + 4 * SZ);
  u16* k_l  = (u16*)(ws + 5 * SZ);
  u16* v_h  = (u16*)(ws + 6 * SZ);
  u16* wqkv_h = (u16*)(ws + 7 * SZ);
  u16* wqkv_l = wqkv_h + (size_t)1536 * 512;
  u16* wo_h   = wqkv_l + (size_t)1536 * 512;
  u16* wo_l   = wo_h + (size_t)512 * 512;

  split_plain<<<768, 256, 0, stream>>>(w_qkv, wqkv_h, wqkv_l, (1536 * 512) / 4);
  split_plain<<<256, 256, 0, stream>>>(w_o, wo_h, wo_l, (512 * 512) / 4);
  transpose_split<<<dim3(16, 8, 8), 256, 0, stream>>>(x, xt_h, xt_l);

  gemm_hilo<1><<<dim3(8, 12, 8), 256, 0, stream>>>(
      wqkv_h, wqkv_l, xt_h, xt_l, b_qkv,
      (void*)q_h, (void*)q_l, (void*)k_h, (void*)k_l, (void*)v_h);

  attn_mfma<<<dim3(16, 8, 8), 256, 0, stream>>>(
      q_h, q_l, k_h, k_l, v_h, xt_h, xt_l);   // avt aliases xt

  gemm_hilo<0><<<dim3(8, 4, 8), 256, 0, stream>>>(
      wo_h, wo_l, xt_h, xt_l, b_o,
      (void*)out, nullptr, nullptr, nullptr, nullptr);
}